// Round 1
// 898.535 us; speedup vs baseline: 1.3838x; 1.3838x over previous
//
#include <hip/hip_runtime.h>
#include <math.h>
#include <stdint.h>

#define EPS 1e-5f

typedef __bf16 bf16x8 __attribute__((ext_vector_type(8)));
typedef __bf16 bf16x4 __attribute__((ext_vector_type(4)));
typedef float  f32x4  __attribute__((ext_vector_type(4)));

constexpr int D  = 1024;   // hidden dim (fixed by the reference)
constexpr int BM = 128;    // M tile
constexpr int BN = 128;    // N tile

// ---------------------------------------------------------------------------
// FAST PATH kernels (need ~71 MB workspace)
// ---------------------------------------------------------------------------
// Pre-pass: per row compute sum(v*v), projection scale s, write bf16(s*v)
// and q = s^2 * sumsq (projected squared norm). One 256-thread block per row.
__global__ __launch_bounds__(256) void project_convert_kernel(
    const float* __restrict__ src, __bf16* __restrict__ dst,
    float* __restrict__ q_out)
{
    const int row = blockIdx.x;
    const int t = threadIdx.x;
    const float4 v = *(const float4*)(src + (size_t)row * D + t * 4);
    float s = v.x * v.x + v.y * v.y + v.z * v.z + v.w * v.w;
#pragma unroll
    for (int off = 32; off > 0; off >>= 1) s += __shfl_down(s, off);
    __shared__ float partial[4];
    __shared__ float s_scale;
    if ((t & 63) == 0) partial[t >> 6] = s;
    __syncthreads();
    if (t == 0) {
        float tot = partial[0] + partial[1] + partial[2] + partial[3];
        float norm = sqrtf(tot);
        float sc = fminf((1.0f - EPS) / (norm + 1e-10f), 1.0f);
        s_scale = sc;
        q_out[row] = sc * sc * tot;   // projected ||.||^2, fp32-exact path
    }
    __syncthreads();
    const float sc = s_scale;
    bf16x4 o = { (__bf16)(v.x * sc), (__bf16)(v.y * sc),
                 (__bf16)(v.z * sc), (__bf16)(v.w * sc) };
    *(bf16x4*)(dst + (size_t)row * D + t * 4) = o;
}

// async global->LDS, 16 B per lane. LDS dest must be wave-uniform base + lane*16.
__device__ __forceinline__ void gload16(const void* g, void* l)
{
    __builtin_amdgcn_global_load_lds(
        (const __attribute__((address_space(1))) uint32_t*)g,
        (__attribute__((address_space(3))) uint32_t*)l, 16, 0, 0);
}

// bf16 GEMM with fused hyperbolic-distance epilogue.
// BK=64 (128 B rows). LDS layout: linear [128][64] bf16 per operand, with the
// 16B-granule XOR swizzle  g_phys = g_log ^ (row & 7)  realized by permuting
// the per-lane GLOBAL source address (rule 21: linear dest + inverse-swz source
// + swz on read; g^=(row&7) is an involution).  ds_read_b128 fragment reads are
// then 2-way-per-bank within each 16-lane quarter = conflict-free (m136).
__global__ __launch_bounds__(256, 3) void hyp_gemm_bf16_kernel(
    const __bf16* __restrict__ Xb, const __bf16* __restrict__ Yb,
    const float* __restrict__ xq, const float* __restrict__ yq,
    float* __restrict__ out, int V, int nbx)
{
    constexpr int BK   = 64;        // bf16 elems per K-tile
    constexpr int KT   = D / BK;    // 16 iterations
    constexpr int ROWB = BK * 2;    // 128 B per LDS row

    __shared__ __bf16 As[BM * BK];  // 16 KB
    __shared__ __bf16 Bs[BN * BK];  // 16 KB

    // XCD-chunked bijective swizzle (gridDim.x % 8 == 0 here)
    const int wg = blockIdx.x;
    const int c = (gridDim.x & 7) ? wg : ((wg & 7) * (gridDim.x >> 3) + (wg >> 3));
    const int m0 = (c / nbx) * BM;
    const int n0 = (c % nbx) * BN;

    const int t = threadIdx.x;

    // ---- staging map: thread t covers rows rt+32j (j=0..3), 16B granule t&7
    const int rt = t >> 3;                   // 0..31
    const int gsrc = (t & 7) ^ (rt & 7);     // pre-swizzled source granule
    const char* xg = (const char*)(Xb + (size_t)(m0 + rt) * D) + gsrc * 16;
    const char* yg = (const char*)(Yb + (size_t)(n0 + rt) * D) + gsrc * 16;
    char* la = (char*)As + t * 16;           // + j*4096 ; = row*128 + (t&7)*16
    char* lb = (char*)Bs + t * 16;

    // ---- wave/fragment map
    const int lane = t & 63;
    const int ln   = lane & 15;
    const int quad = lane >> 4;
    const int wave = t >> 6;
    const int wm = (wave & 1) * 64;
    const int wn = (wave >> 1) * 64;
    const int swz = ln & 7;                  // row&7 of every fragment row

    f32x4 acc[4][4] = {};

#pragma unroll
    for (int kt = 0; kt < KT; ++kt) {
        __syncthreads();                     // prev iter's ds_reads done
        const int ko = kt * 128;             // byte offset along a row
#pragma unroll
        for (int j = 0; j < 4; ++j) {
            gload16(xg + j * 65536 + ko, la + j * 4096);
            gload16(yg + j * 65536 + ko, lb + j * 4096);
        }
        __syncthreads();                     // vmcnt(0) drain: tile resident
#pragma unroll
        for (int ks = 0; ks < 2; ++ks) {
            bf16x8 af[4], bfr[4];
#pragma unroll
            for (int i = 0; i < 4; ++i) {
                const int ga = ((ks * 4 + quad) ^ swz) * 16;
                af[i]  = *(const bf16x8*)((const char*)As + (wm + i * 16 + ln) * ROWB + ga);
                bfr[i] = *(const bf16x8*)((const char*)Bs + (wn + i * 16 + ln) * ROWB + ga);
            }
#pragma unroll
            for (int mt = 0; mt < 4; ++mt)
#pragma unroll
                for (int nt = 0; nt < 4; ++nt)
                    acc[mt][nt] = __builtin_amdgcn_mfma_f32_16x16x32_bf16(
                        af[mt], bfr[nt], acc[mt][nt], 0, 0, 0);
        }
    }

    // ---------------- epilogue: hyperbolic distance ----------------
    // C/D layout: col = lane&15, row = quad*4 + reg  [m89-verified]
    float yqv[4], omy[4];
    int gcv[4];
#pragma unroll
    for (int nt = 0; nt < 4; ++nt) {
        const int gc = n0 + wn + nt * 16 + ln;
        gcv[nt] = gc;
        yqv[nt] = yq[gc];
        omy[nt] = 1.0f - yqv[nt];
    }
#pragma unroll
    for (int mt = 0; mt < 4; ++mt) {
#pragma unroll
        for (int r = 0; r < 4; ++r) {
            const int gm = m0 + wm + mt * 16 + quad * 4 + r;
            const float xqv = xq[gm];
            const float omx = 1.0f - xqv;
            float* orow = out + (size_t)gm * V;
#pragma unroll
            for (int nt = 0; nt < 4; ++nt) {
                const float dot = acc[mt][nt][r];   // already projected dot
                float d2 = fmaxf(xqv + yqv[nt] - 2.0f * dot, 0.0f);
                float d  = __builtin_amdgcn_sqrtf(d2);
                float denom = omx * omy[nt] + EPS;
                float w = d * __builtin_amdgcn_rcpf(denom);   // t/2, t=2d/denom
                float res;
                if (__builtin_expect(w >= 4.0f, 1)) {
                    // arccosh(1+t) = log(2+2t) - 1/(4(t+1)^2); t>=8 => err<4e-3
                    res = __logf(2.0f + 4.0f * w);
                } else {
                    float arg = fmaxf(1.0f + 2.0f * w, 1.0f + EPS);
                    res = __logf(arg + __builtin_amdgcn_sqrtf(arg * arg - 1.0f));
                }
                orow[gcv[nt]] = -res;
            }
        }
    }
}

// ---------------------------------------------------------------------------
// FALLBACK PATH (previous verified kernels; used if workspace is too small)
// ---------------------------------------------------------------------------
constexpr int LDT = 40;  // 32 + 8 padded LDS row stride (bf16)

__global__ __launch_bounds__(256) void row_stats_kernel(
    const float* __restrict__ src, float* __restrict__ scale_out,
    float* __restrict__ sq_out)
{
    const int row = blockIdx.x;
    const int t = threadIdx.x;
    const float4 v = *(const float4*)(src + (size_t)row * D + t * 4);
    float s = v.x * v.x + v.y * v.y + v.z * v.z + v.w * v.w;
#pragma unroll
    for (int off = 32; off > 0; off >>= 1) s += __shfl_down(s, off);
    __shared__ float partial[4];
    if ((t & 63) == 0) partial[t >> 6] = s;
    __syncthreads();
    if (t == 0) {
        float tot = partial[0] + partial[1] + partial[2] + partial[3];
        float norm = sqrtf(tot);
        float sc = fminf((1.0f - EPS) / (norm + 1e-10f), 1.0f);
        scale_out[row] = sc;
        sq_out[row] = sc * sc * tot;
    }
}

__global__ __launch_bounds__(256) void hyp_gemm_kernel(
    const float* __restrict__ X, const float* __restrict__ Y,
    const float* __restrict__ sx, const float* __restrict__ xq,
    const float* __restrict__ sy, const float* __restrict__ yq,
    float* __restrict__ out, int V)
{
    constexpr int BK = 32;
    __shared__ __bf16 As[BM * LDT];
    __shared__ __bf16 Bs[BN * LDT];

    const int t  = threadIdx.x;
    const int m0 = blockIdx.y * BM;
    const int n0 = blockIdx.x * BN;

    const int sr = t >> 3;
    const int scol = t & 7;

    const float* xg = X + (size_t)(m0 + sr) * D + scol * 4;
    const float* yg = Y + (size_t)(n0 + sr) * D + scol * 4;

    const int lane = t & 63;
    const int wave = t >> 6;
    const int wm = (wave & 1) * 64;
    const int wn = (wave >> 1) * 64;
    const int ln = lane & 15;
    const int quad = lane >> 4;

    f32x4 acc[4][4] = {};

    float4 pa[4], pb[4];
#pragma unroll
    for (int j = 0; j < 4; ++j) {
        pa[j] = *(const float4*)(xg + (size_t)j * 32 * D);
        pb[j] = *(const float4*)(yg + (size_t)j * 32 * D);
    }

    constexpr int KT = D / BK;
    for (int kt = 0; kt < KT; ++kt) {
        __syncthreads();
#pragma unroll
        for (int j = 0; j < 4; ++j) {
            bf16x4 a4 = { (__bf16)pa[j].x, (__bf16)pa[j].y, (__bf16)pa[j].z, (__bf16)pa[j].w };
            bf16x4 b4 = { (__bf16)pb[j].x, (__bf16)pb[j].y, (__bf16)pb[j].z, (__bf16)pb[j].w };
            *(bf16x4*)&As[(sr + 32 * j) * LDT + scol * 4] = a4;
            *(bf16x4*)&Bs[(sr + 32 * j) * LDT + scol * 4] = b4;
        }
        __syncthreads();
        if (kt + 1 < KT) {
            const int koff = (kt + 1) * BK;
#pragma unroll
            for (int j = 0; j < 4; ++j) {
                pa[j] = *(const float4*)(xg + (size_t)j * 32 * D + koff);
                pb[j] = *(const float4*)(yg + (size_t)j * 32 * D + koff);
            }
        }
        bf16x8 af[4], bfr[4];
#pragma unroll
        for (int i = 0; i < 4; ++i) {
            af[i]  = *(const bf16x8*)&As[(wm + i * 16 + ln) * LDT + quad * 8];
            bfr[i] = *(const bf16x8*)&Bs[(wn + i * 16 + ln) * LDT + quad * 8];
        }
#pragma unroll
        for (int mt = 0; mt < 4; ++mt)
#pragma unroll
            for (int nt = 0; nt < 4; ++nt)
                acc[mt][nt] = __builtin_amdgcn_mfma_f32_16x16x32_bf16(
                    af[mt], bfr[nt], acc[mt][nt], 0, 0, 0);
    }

    float yqv[4], syv[4];
    int gcv[4];
#pragma unroll
    for (int nt = 0; nt < 4; ++nt) {
        const int gc = n0 + wn + nt * 16 + ln;
        gcv[nt] = gc;
        yqv[nt] = yq[gc];
        syv[nt] = sy[gc];
    }
#pragma unroll
    for (int mt = 0; mt < 4; ++mt) {
#pragma unroll
        for (int r = 0; r < 4; ++r) {
            const int gm = m0 + wm + mt * 16 + quad * 4 + r;
            const float xqv = xq[gm];
            const float sxv = sx[gm];
            const float omx = 1.0f - xqv;
            float* orow = out + (size_t)gm * V;
#pragma unroll
            for (int nt = 0; nt < 4; ++nt) {
                const float raw = acc[mt][nt][r];
                const float dot = sxv * syv[nt] * raw;
                float d2 = xqv + yqv[nt] - 2.0f * dot;
                float dd = __builtin_amdgcn_sqrtf(fmaxf(d2, 0.0f));
                float denom = omx * (1.0f - yqv[nt]) + EPS;
                float arg = 1.0f + 2.0f * dd * __builtin_amdgcn_rcpf(denom);
                arg = fmaxf(arg, 1.0f + EPS);
                float res = -__logf(arg + __builtin_amdgcn_sqrtf(arg * arg - 1.0f));
                orow[gcv[nt]] = res;
            }
        }
    }
}

// ---------------------------------------------------------------------------
extern "C" void kernel_launch(void* const* d_in, const int* in_sizes, int n_in,
                              void* d_out, int out_size, void* d_ws, size_t ws_size,
                              hipStream_t stream)
{
    const float* X = (const float*)d_in[0];   // hidden_states (N x D) fp32
    const float* Y = (const float*)d_in[1];   // weight        (V x D) fp32
    float* out = (float*)d_out;               // logits (N x V) fp32

    const int N = in_sizes[0] / D;   // 4096
    const int V = in_sizes[1] / D;   // 32000

    // fast path workspace: bf16 X (N*D) + bf16 Y (V*D) + xq (N) + yq (V)
    const size_t need = (size_t)(N + V) * D * 2 + (size_t)(N + V) * 4;

    if (ws_size >= need && (N % BM) == 0 && (V % BN) == 0) {
        __bf16* Xb = (__bf16*)d_ws;
        __bf16* Yb = Xb + (size_t)N * D;
        float* xq = (float*)(Yb + (size_t)V * D);
        float* yq = xq + N;

        project_convert_kernel<<<N, 256, 0, stream>>>(X, Xb, xq);
        project_convert_kernel<<<V, 256, 0, stream>>>(Y, Yb, yq);

        const int nbx = V / BN;
        const int nwg = nbx * (N / BM);
        hyp_gemm_bf16_kernel<<<nwg, 256, 0, stream>>>(Xb, Yb, xq, yq, out, V, nbx);
    } else {
        float* sx = (float*)d_ws;
        float* xq = sx + N;
        float* sy = xq + N;
        float* yq = sy + V;

        row_stats_kernel<<<N, 256, 0, stream>>>(X, sx, xq);
        row_stats_kernel<<<V, 256, 0, stream>>>(Y, sy, yq);

        dim3 grid(V / BN, N / BM);
        hyp_gemm_kernel<<<grid, 256, 0, stream>>>(X, Y, sx, xq, sy, yq, out, V);
    }
}